// Round 5
// baseline (51.469 us; speedup 1.0000x reference)
//
#include <hip/hip_runtime.h>
#include <math.h>

#define NSENT 256
#define SLEN  512
#define VROWS 50000
#define EDIM  300
#define NC4   75               // EDIM / 4 (float4s per row)
#define NROW  12               // 3 + 4 + 5 conv rows
#define TROWS 64               // vocab rows per tile
#define TF4   (TROWS * NC4)    // 4800 float4s per tile
#define LDS_S4 77              // padded LDS row stride in float4 (4*77%32=20 -> conflict-free)

// ---------------------------------------------------------------------------
// Kernel A: vocab scores  s[v][r] = dot(emb_table[v], k_row_r)
// Block = 256 threads, 128 rows as 2 tiles of 64.
// Loads are FLAT-COALESCED (wave reads 1KB contiguous = 8 lines/instr instead
// of 64 scattered lines), staged regs -> LDS transpose tile (padded stride).
// Tile t+1 loads issue before tile t compute (async-stage overlap).
// ---------------------------------------------------------------------------
__global__ __launch_bounds__(256, 1)
void vocab_scores(const float* __restrict__ emb,
                  const float* __restrict__ k3,
                  const float* __restrict__ k4,
                  const float* __restrict__ k5,
                  float* __restrict__ s)
{
    __shared__ float4 ebuf[TROWS * LDS_S4];   // 78848 B
    __shared__ float  part[4][TROWS][13];     // 13312 B
    __shared__ float  red[TROWS * 13];        //  3328 B

    const int tid   = threadIdx.x;
    const int lane  = tid & 63;
    const int wave  = tid >> 6;
    const int chunk = __builtin_amdgcn_readfirstlane(wave);  // scalar k-indices
    const int c0    = chunk * 19;
    const bool full = (chunk < 3);            // chunks 0..2: 19 cols, chunk 3: 18

    const float4* embf4 = reinterpret_cast<const float4*>(emb);
    const float4* k3v   = reinterpret_cast<const float4*>(k3);
    const float4* k4v   = reinterpret_cast<const float4*>(k4);
    const float4* k5v   = reinterpret_cast<const float4*>(k5);

    const int row00 = blockIdx.x * (2 * TROWS);

    float4 pre[19];   // staging registers (19*256 = 4864 >= 4800, tail masked)

    auto issue_loads = [&](int tile_row0) {
        #pragma unroll
        for (int k = 0; k < 19; ++k) {
            const int g = k * 256 + tid;
            float4 v = make_float4(0.f, 0.f, 0.f, 0.f);
            if (g < TF4 && (tile_row0 + g / NC4) < VROWS)
                v = embf4[tile_row0 * NC4 + g];   // coalesced flat stream
            pre[k] = v;
        }
    };

    auto write_lds = [&]() {
        #pragma unroll
        for (int k = 0; k < 19; ++k) {
            const int g = k * 256 + tid;
            if (g < TF4)
                ebuf[(g / NC4) * LDS_S4 + (g % NC4)] = pre[k];
        }
    };

    auto fma_col = [&](float acc[NROW], const float4 ev, int c) {
        #pragma unroll
        for (int r = 0; r < 3; ++r) {
            const float4 kv = k3v[r * NC4 + c];     // wave-uniform -> s_load
            acc[r] = fmaf(ev.x, kv.x, acc[r]);
            acc[r] = fmaf(ev.y, kv.y, acc[r]);
            acc[r] = fmaf(ev.z, kv.z, acc[r]);
            acc[r] = fmaf(ev.w, kv.w, acc[r]);
        }
        #pragma unroll
        for (int r = 0; r < 4; ++r) {
            const float4 kv = k4v[r * NC4 + c];
            acc[3+r] = fmaf(ev.x, kv.x, acc[3+r]);
            acc[3+r] = fmaf(ev.y, kv.y, acc[3+r]);
            acc[3+r] = fmaf(ev.z, kv.z, acc[3+r]);
            acc[3+r] = fmaf(ev.w, kv.w, acc[3+r]);
        }
        #pragma unroll
        for (int r = 0; r < 5; ++r) {
            const float4 kv = k5v[r * NC4 + c];
            acc[7+r] = fmaf(ev.x, kv.x, acc[7+r]);
            acc[7+r] = fmaf(ev.y, kv.y, acc[7+r]);
            acc[7+r] = fmaf(ev.z, kv.z, acc[7+r]);
            acc[7+r] = fmaf(ev.w, kv.w, acc[7+r]);
        }
    };

    auto compute_store = [&](int tile_row0) {
        float acc[NROW];
        #pragma unroll
        for (int r = 0; r < NROW; ++r) acc[r] = 0.f;

        // lane-row LDS reads: stride 77 f4 -> all 32 banks tiled, conflict-free
        #pragma unroll
        for (int i = 0; i < 18; ++i)
            fma_col(acc, ebuf[lane * LDS_S4 + c0 + i], c0 + i);
        if (full)
            fma_col(acc, ebuf[lane * LDS_S4 + c0 + 18], c0 + 18);

        #pragma unroll
        for (int r = 0; r < NROW; ++r) part[wave][lane][r] = acc[r];
        __syncthreads();

        const int r0 = wave * 3;
        #pragma unroll
        for (int rr = 0; rr < 3; ++rr) {
            const int r = r0 + rr;
            red[lane * 13 + r] = part[0][lane][r] + part[1][lane][r] +
                                 part[2][lane][r] + part[3][lane][r];
        }
        __syncthreads();

        for (int j = tid; j < TROWS * NROW; j += 256) {
            const int gi = tile_row0 * NROW + j;
            if (gi < VROWS * NROW)
                s[gi] = red[(j / NROW) * 13 + (j % NROW)];
        }
    };

    // ---- 2-tile pipeline (single LDS buffer, register prefetch) ------------
    issue_loads(row00);                // tile 0 loads (coalesced)
    write_lds();                       // vmcnt drain + transpose into LDS
    __syncthreads();
    issue_loads(row00 + TROWS);        // tile 1 loads: drain under tile 0 FMA
    compute_store(row00);              // ends with barrier after red reads
    write_lds();                       // ebuf free; pre[] ready (vmcnt auto)
    __syncthreads();
    compute_store(row00 + TROWS);
}

// ---------------------------------------------------------------------------
// Kernel B: gather 48B/token from L2/L3-resident score table, then
// windows + tanh + max + fc + log_softmax. One block (1024 thr) per sentence.
// ---------------------------------------------------------------------------
__global__ __launch_bounds__(1024, 1)
void textcnn_finish(const int*   __restrict__ sent,
                    const float* __restrict__ s,
                    const float* __restrict__ b3,
                    const float* __restrict__ b4,
                    const float* __restrict__ b5,
                    const float* __restrict__ fcw,
                    const float* __restrict__ fcb,
                    float* __restrict__ out)
{
    __shared__ float s_lds[NROW * SLEN];
    __shared__ float red[8][3];

    const int b = blockIdx.x;
    const int t = threadIdx.x;

    auto gather = [&](int token, int j) {
        const int widx = sent[b * SLEN + token];
        const float4 v = reinterpret_cast<const float4*>(s + (size_t)widx * NROW)[j];
        s_lds[(4*j + 0) * SLEN + token] = v.x;
        s_lds[(4*j + 1) * SLEN + token] = v.y;
        s_lds[(4*j + 2) * SLEN + token] = v.z;
        s_lds[(4*j + 3) * SLEN + token] = v.w;
    };

    gather(t & 511, t >> 9);            // j = 0,1 across the 1024 threads
    if (t < SLEN) gather(t, 2);         // j = 2
    __syncthreads();

    if (t < SLEN) {
        const float bb3 = b3[0], bb4 = b4[0], bb5 = b5[0];
        float m3 = -1e30f, m4 = -1e30f, m5 = -1e30f;
        if (t < SLEN - 2)
            m3 = tanhf(s_lds[0*SLEN + t] + s_lds[1*SLEN + t+1] +
                       s_lds[2*SLEN + t+2] + bb3);
        if (t < SLEN - 3)
            m4 = tanhf(s_lds[3*SLEN + t] + s_lds[4*SLEN + t+1] +
                       s_lds[5*SLEN + t+2] + s_lds[6*SLEN + t+3] + bb4);
        if (t < SLEN - 4)
            m5 = tanhf(s_lds[7*SLEN + t] + s_lds[8*SLEN + t+1] +
                       s_lds[9*SLEN + t+2] + s_lds[10*SLEN + t+3] +
                       s_lds[11*SLEN + t+4] + bb5);

        #pragma unroll
        for (int off = 32; off; off >>= 1) {
            m3 = fmaxf(m3, __shfl_xor(m3, off));
            m4 = fmaxf(m4, __shfl_xor(m4, off));
            m5 = fmaxf(m5, __shfl_xor(m5, off));
        }
        if ((t & 63) == 0) {
            const int w = t >> 6;
            red[w][0] = m3; red[w][1] = m4; red[w][2] = m5;
        }
    }
    __syncthreads();

    if (t == 0) {
        float f3 = red[0][0], f4 = red[0][1], f5 = red[0][2];
        #pragma unroll
        for (int w = 1; w < 8; ++w) {
            f3 = fmaxf(f3, red[w][0]);
            f4 = fmaxf(f4, red[w][1]);
            f5 = fmaxf(f5, red[w][2]);
        }
        float lg[10];
        float mx = -1e30f;
        #pragma unroll
        for (int c = 0; c < 10; ++c) {
            lg[c] = fcb[c] + f3 * fcw[c*3+0] + f4 * fcw[c*3+1] + f5 * fcw[c*3+2];
            mx = fmaxf(mx, lg[c]);
        }
        float ssum = 0.f;
        #pragma unroll
        for (int c = 0; c < 10; ++c) ssum += expf(lg[c] - mx);
        const float lse = logf(ssum);
        #pragma unroll
        for (int c = 0; c < 10; ++c) out[b * 10 + c] = lg[c] - mx - lse;
    }
}

extern "C" void kernel_launch(void* const* d_in, const int* in_sizes, int n_in,
                              void* d_out, int out_size, void* d_ws, size_t ws_size,
                              hipStream_t stream) {
    const int*   sent = (const int*)  d_in[0];
    const float* emb  = (const float*)d_in[1];
    const float* k3   = (const float*)d_in[2];
    const float* b3   = (const float*)d_in[3];
    const float* k4   = (const float*)d_in[4];
    const float* b4   = (const float*)d_in[5];
    const float* k5   = (const float*)d_in[6];
    const float* b5   = (const float*)d_in[7];
    const float* fcw  = (const float*)d_in[8];
    const float* fcb  = (const float*)d_in[9];
    float* out = (float*)d_out;
    float* s   = (float*)d_ws;        // VROWS * 12 * 4 B = 2.4 MB

    const int nblk = (VROWS + 2 * TROWS - 1) / (2 * TROWS);   // 391
    vocab_scores<<<nblk, 256, 0, stream>>>(emb, k3, k4, k5, s);
    textcnn_finish<<<NSENT, 1024, 0, stream>>>(sent, s, b3, b4, b5, fcw, fcb, out);
}

// Round 6
// 28.977 us; speedup vs baseline: 1.7762x; 1.7762x over previous
//
#include <hip/hip_runtime.h>
#include <hip/hip_bf16.h>
#include <math.h>

#define NSENT 256
#define SLEN  512
#define VROWS 50000
#define EDIM  300
#define NROW  12
#define NSTEP 10          // ceil(300/32) K-steps of the 16x16x32 MFMA

typedef __attribute__((ext_vector_type(8))) short bf16x8;
typedef __attribute__((ext_vector_type(4))) float f32x4;

static __device__ __forceinline__ short f2bf(float f) {
    __hip_bfloat16 h = __float2bfloat16(f);   // RNE; compiler emits cvt_pk pairs
    short s;
    __builtin_memcpy(&s, &h, sizeof(s));
    return s;
}

// ---------------------------------------------------------------------------
// Kernel A: vocab scores  s[v][r] = dot(emb_table[v], k_row_r)  as bf16 MFMA.
// [V,300] x [300,12] GEMM. Block = 4 waves; wave owns a 16-row M-tile.
// A-frag: lane holds emb[vbase+(lane&15)][k=(lane>>4)*8+j], j=0..7 -> 2 f4
// loads per K-step, all 20 batched for MLP (16 distinct lines per instr).
// B-frag: kv rows ARE B^T ([col][K]) -> same fragment pattern, tiny/L1-hot.
// D: col=lane&15, row=(lane>>4)*4+reg  (m89-verified layout).
// ---------------------------------------------------------------------------
__global__ __launch_bounds__(256, 2)
void vocab_scores_mfma(const float* __restrict__ emb,
                       const float* __restrict__ k3,
                       const float* __restrict__ k4,
                       const float* __restrict__ k5,
                       float* __restrict__ s)
{
    const int lane = threadIdx.x & 63;
    const int wave = threadIdx.x >> 6;
    const int rc   = lane & 15;     // A-row-in-tile / B-col / D-col
    const int kg   = lane >> 4;     // k-group 0..3

    const int vbase = blockIdx.x * 64 + wave * 16;
    const int vrow  = min(vbase + rc, VROWS - 1);   // clamp tail; stores guarded

    // ---- B fragments: conv-kernel row rc (cols 12..15 are zero padding) ---
    const float* krow = nullptr;
    if      (rc < 3)  krow = k3 + rc * EDIM;
    else if (rc < 7)  krow = k4 + (rc - 3) * EDIM;
    else if (rc < 12) krow = k5 + (rc - 7) * EDIM;

    bf16x8 bfrag[NSTEP];
    #pragma unroll
    for (int st = 0; st < NSTEP; ++st) {
        const int k0 = st * 32 + kg * 8;
        float4 b0 = make_float4(0.f,0.f,0.f,0.f);
        float4 b1 = make_float4(0.f,0.f,0.f,0.f);
        if (krow) {
            if (k0 + 4 <= EDIM) b0 = *reinterpret_cast<const float4*>(krow + k0);
            if (k0 + 8 <= EDIM) b1 = *reinterpret_cast<const float4*>(krow + k0 + 4);
        }
        bf16x8 f;
        f[0]=f2bf(b0.x); f[1]=f2bf(b0.y); f[2]=f2bf(b0.z); f[3]=f2bf(b0.w);
        f[4]=f2bf(b1.x); f[5]=f2bf(b1.y); f[6]=f2bf(b1.z); f[7]=f2bf(b1.w);
        bfrag[st] = f;
    }

    // ---- A loads: batch all 20 float4 (deep MLP, lines consumed once) -----
    const float* arow = emb + (size_t)vrow * EDIM;
    float4 a0[NSTEP], a1[NSTEP];
    #pragma unroll
    for (int st = 0; st < NSTEP; ++st) {
        const int k0 = st * 32 + kg * 8;
        a0[st] = (k0 + 4 <= EDIM) ? *reinterpret_cast<const float4*>(arow + k0)
                                  : make_float4(0.f,0.f,0.f,0.f);
        a1[st] = (k0 + 8 <= EDIM) ? *reinterpret_cast<const float4*>(arow + k0 + 4)
                                  : make_float4(0.f,0.f,0.f,0.f);
    }

    // ---- 10 MFMA K-steps, accumulate in one f32x4 -------------------------
    f32x4 acc = {0.f, 0.f, 0.f, 0.f};
    #pragma unroll
    for (int st = 0; st < NSTEP; ++st) {
        bf16x8 af;
        af[0]=f2bf(a0[st].x); af[1]=f2bf(a0[st].y);
        af[2]=f2bf(a0[st].z); af[3]=f2bf(a0[st].w);
        af[4]=f2bf(a1[st].x); af[5]=f2bf(a1[st].y);
        af[6]=f2bf(a1[st].z); af[7]=f2bf(a1[st].w);
        acc = __builtin_amdgcn_mfma_f32_16x16x32_bf16(af, bfrag[st], acc, 0, 0, 0);
    }

    // ---- store D ----------------------------------------------------------
    if (rc < NROW) {
        #pragma unroll
        for (int j = 0; j < 4; ++j) {
            const int v = vbase + kg * 4 + j;
            if (v < VROWS) s[(size_t)v * NROW + rc] = acc[j];
        }
    }
}

// ---------------------------------------------------------------------------
// Kernel B: gather 48B/token from L2/L3-resident score table, then
// windows + tanh + max + fc + log_softmax. One block (1024 thr) per sentence.
// ---------------------------------------------------------------------------
__global__ __launch_bounds__(1024, 1)
void textcnn_finish(const int*   __restrict__ sent,
                    const float* __restrict__ s,
                    const float* __restrict__ b3,
                    const float* __restrict__ b4,
                    const float* __restrict__ b5,
                    const float* __restrict__ fcw,
                    const float* __restrict__ fcb,
                    float* __restrict__ out)
{
    __shared__ float s_lds[NROW * SLEN];
    __shared__ float red[8][3];

    const int b = blockIdx.x;
    const int t = threadIdx.x;

    auto gather = [&](int token, int j) {
        const int widx = sent[b * SLEN + token];
        const float4 v = reinterpret_cast<const float4*>(s + (size_t)widx * NROW)[j];
        s_lds[(4*j + 0) * SLEN + token] = v.x;
        s_lds[(4*j + 1) * SLEN + token] = v.y;
        s_lds[(4*j + 2) * SLEN + token] = v.z;
        s_lds[(4*j + 3) * SLEN + token] = v.w;
    };

    gather(t & 511, t >> 9);            // j = 0,1 across the 1024 threads
    if (t < SLEN) gather(t, 2);         // j = 2
    __syncthreads();

    if (t < SLEN) {
        const float bb3 = b3[0], bb4 = b4[0], bb5 = b5[0];
        float m3 = -1e30f, m4 = -1e30f, m5 = -1e30f;
        if (t < SLEN - 2)
            m3 = tanhf(s_lds[0*SLEN + t] + s_lds[1*SLEN + t+1] +
                       s_lds[2*SLEN + t+2] + bb3);
        if (t < SLEN - 3)
            m4 = tanhf(s_lds[3*SLEN + t] + s_lds[4*SLEN + t+1] +
                       s_lds[5*SLEN + t+2] + s_lds[6*SLEN + t+3] + bb4);
        if (t < SLEN - 4)
            m5 = tanhf(s_lds[7*SLEN + t] + s_lds[8*SLEN + t+1] +
                       s_lds[9*SLEN + t+2] + s_lds[10*SLEN + t+3] +
                       s_lds[11*SLEN + t+4] + bb5);

        #pragma unroll
        for (int off = 32; off; off >>= 1) {
            m3 = fmaxf(m3, __shfl_xor(m3, off));
            m4 = fmaxf(m4, __shfl_xor(m4, off));
            m5 = fmaxf(m5, __shfl_xor(m5, off));
        }
        if ((t & 63) == 0) {
            const int w = t >> 6;
            red[w][0] = m3; red[w][1] = m4; red[w][2] = m5;
        }
    }
    __syncthreads();

    if (t == 0) {
        float f3 = red[0][0], f4 = red[0][1], f5 = red[0][2];
        #pragma unroll
        for (int w = 1; w < 8; ++w) {
            f3 = fmaxf(f3, red[w][0]);
            f4 = fmaxf(f4, red[w][1]);
            f5 = fmaxf(f5, red[w][2]);
        }
        float lg[10];
        float mx = -1e30f;
        #pragma unroll
        for (int c = 0; c < 10; ++c) {
            lg[c] = fcb[c] + f3 * fcw[c*3+0] + f4 * fcw[c*3+1] + f5 * fcw[c*3+2];
            mx = fmaxf(mx, lg[c]);
        }
        float ssum = 0.f;
        #pragma unroll
        for (int c = 0; c < 10; ++c) ssum += expf(lg[c] - mx);
        const float lse = logf(ssum);
        #pragma unroll
        for (int c = 0; c < 10; ++c) out[b * 10 + c] = lg[c] - mx - lse;
    }
}

extern "C" void kernel_launch(void* const* d_in, const int* in_sizes, int n_in,
                              void* d_out, int out_size, void* d_ws, size_t ws_size,
                              hipStream_t stream) {
    const int*   sent = (const int*)  d_in[0];
    const float* emb  = (const float*)d_in[1];
    const float* k3   = (const float*)d_in[2];
    const float* b3   = (const float*)d_in[3];
    const float* k4   = (const float*)d_in[4];
    const float* b4   = (const float*)d_in[5];
    const float* k5   = (const float*)d_in[6];
    const float* b5   = (const float*)d_in[7];
    const float* fcw  = (const float*)d_in[8];
    const float* fcb  = (const float*)d_in[9];
    float* out = (float*)d_out;
    float* s   = (float*)d_ws;        // VROWS * 12 * 4 B = 2.4 MB

    const int nblk = (VROWS + 63) / 64;   // 782 blocks, 64 rows each
    vocab_scores_mfma<<<nblk, 256, 0, stream>>>(emb, k3, k4, k5, s);
    textcnn_finish<<<NSENT, 1024, 0, stream>>>(sent, s, b3, b4, b5, fcw, fcb, out);
}